// Round 5
// baseline (316.454 us; speedup 1.0000x reference)
//
#include <hip/hip_runtime.h>

// Pipeline (7 launches): k_zero -> k_score (async LDS staging + fused global histogram)
//                        -> k_topsel (B-find+compact+sort+gather) -> k_ioumat -> k_greedy
//                        -> k_loss -> k_final
// R1: k_topsel phase D hybrid register/shuffle bitonic (10 LDS stages + 56 barrier-free).
// R4: k_score NT staging; k_greedy hoisted unconditional row gather.
// R5: histogram fused into k_score (global per-task hist, 1 atomic/anchor; invalid lanes
//     wave-aggregated). k_topsel drops phase A + 64KB LDS h32; phase C keys preloaded to
//     registers under phase B's hist read; B-threshold walk runs in owning thread's regs.

static constexpr int NB   = 8;
static constexpr int NA   = 25200;
static constexpr int NCLS = 80;
static constexpr int CH   = 85;
static constexpr int NT   = 16;    // 8 clean + 8 patch tasks
static constexpr int KMAX = 1024;
static constexpr int NBIN = 32768; // 15-bit prefix bins
static constexpr int PSH  = 17;    // key >> PSH = bin
static constexpr int CAP  = 2048;  // candidate buffer (hi[0,1024) eq[1024,2048))
static constexpr int IOB  = 34;    // x-blocks for k_ioumat (patch: 136 pairs*64 rows = 34*256)

// workspace byte offsets (all 16B aligned)
static constexpr size_t OFF_KEYS = 0;                                     // 1,612,800
static constexpr size_t OFF_CLS  = OFF_KEYS + (size_t)NT * NA * 4;        // 1,612,800
static constexpr size_t OFF_BOX  = OFF_CLS  + (size_t)NT * NA * 4;        // 262,144
static constexpr size_t OFF_CLSK = OFF_BOX  + (size_t)NT * KMAX * 16;     // 65,536
static constexpr size_t OFF_VALK = OFF_CLSK + (size_t)NT * KMAX * 4;      // 65,536
static constexpr size_t OFF_KEEP = OFF_VALK + (size_t)NT * KMAX * 4;      // 2,048
static constexpr size_t OFF_SUP  = OFF_KEEP + (size_t)NT * 16 * 8;        // 2,097,152
static constexpr size_t OFF_DIAG = OFF_SUP  + (size_t)NT * KMAX * 16 * 8; // 131,072
static constexpr size_t OFF_PART = OFF_DIAG + (size_t)NT * KMAX * 8;      // 512
static constexpr size_t OFF_HIST = OFF_PART + 512;                        // 2,097,152 (16*32768*4)
// total ~8 MB

__device__ __forceinline__ unsigned okey(float f) {
  unsigned u = __float_as_uint(f);
  return (u & 0x80000000u) ? ~u : (u | 0x80000000u);
}

__device__ __forceinline__ unsigned long long shflx64(unsigned long long v, int m) {
  unsigned lo = (unsigned)v, hi = (unsigned)(v >> 32);
  lo = __shfl_xor(lo, m);
  hi = __shfl_xor(hi, m);
  return ((unsigned long long)hi << 32) | lo;
}

// ---------------- K0: zero the global histogram (workspace is re-poisoned each iter) ----------------
__global__ __launch_bounds__(256) void k_zero(uint4* __restrict__ hist4) {
  hist4[blockIdx.x * 256 + threadIdx.x] = make_uint4(0u, 0u, 0u, 0u);
}

// ---------------- K1: per-anchor score/class + fused global histogram ----------------
__global__ __launch_bounds__(256) void k_score(const float* __restrict__ clean,
                                               const float* __restrict__ patch,
                                               unsigned* __restrict__ keys,
                                               int* __restrict__ clsArr,
                                               unsigned* __restrict__ hist) {
#pragma clang fp contract(off)
  __shared__ float rows[4][16 * CH];  // per-wave slices, 4 x 5440 B (no cross-wave sharing)
  const int t    = blockIdx.y;
  const int wave = threadIdx.x >> 6;
  const int lane = threadIdx.x & 63;
  const int a0   = blockIdx.x * 64 + wave * 16;  // this wave's 16 anchors (NA % 16 == 0)
  if (a0 >= NA) return;                          // empty wave in last block only
  const float conf_th = (t < 8) ? 0.25f : 0.001f;
  const float* __restrict__ src = ((t < 8) ? clean : patch) + (size_t)(t & 7) * NA * CH;
  const float4* g4 = (const float4*)(src + (size_t)a0 * CH);  // a0*85 % 4 == 0 -> 16B aligned
  float4* rows4 = (float4*)rows[wave];
  // stage 16*85 = 1360 floats = 340 float4; aux=2 -> NT (no L2/L3 allocate)
#pragma unroll
  for (int c = 0; c < 6; ++c) {
    const int i = (c << 6) + lane;  // lds dst = uniform base + lane*16
    if (i < 340) {
      __builtin_amdgcn_global_load_lds(
          (const __attribute__((address_space(1))) void*)(g4 + i),
          (__attribute__((address_space(3))) void*)(rows4 + (c << 6)),
          16, 0, 2 /* NT */);
    }
  }
  // vmcnt is per-wave: wait only on our own staging loads, no __syncthreads.
  asm volatile("s_waitcnt vmcnt(0)" ::: "memory");
  __builtin_amdgcn_sched_barrier(0);

  const int ar = lane >> 2;  // 0..15
  const int q  = lane & 3;
  const float* r = rows[wave] + ar * CH;
  const float obj = r[4];
  const int c0 = q * 20;
  float best = r[5 + c0] * obj;  // products first (matches ref argmax over cls_conf)
  int bc = c0;
  for (int c = c0 + 1; c < c0 + 20; ++c) {
    float v = r[5 + c] * obj;
    if (v > best) { best = v; bc = c; }
  }
  {
    float b2 = __shfl_down(best, 2); int c2 = __shfl_down(bc, 2);
    if (b2 > best || (b2 == best && c2 < bc)) { best = b2; bc = c2; }
    float b1 = __shfl_down(best, 1); int c1 = __shfl_down(bc, 1);
    if (b1 > best || (b1 == best && c1 < bc)) { best = b1; bc = c1; }
  }
  if (q == 0) {
    const bool valid = (obj > conf_th) && (best > conf_th);
    const float score = valid ? best : -1e30f;
    const unsigned key = okey(score);
    const int a = a0 + ar;
    keys[(size_t)t * NA + a]   = key;
    clsArr[(size_t)t * NA + a] = bc;
    // fused histogram: every anchor adds 1 to its bin (exactly phase A's counts).
    unsigned* ht = hist + (size_t)t * NBIN;
    if (valid) {
      atomicAdd(&ht[key >> PSH], 1u);
    } else {
      // all invalid lanes share one bin -> wave-aggregate to one atomic
      unsigned long long mb = __ballot(true);  // active = (q==0 && !valid)
      if (lane == (int)__ffsll(mb) - 1)
        atomicAdd(&ht[okey(-1e30f) >> PSH], (unsigned)__popcll(mb));
    }
  }
}

// ---------------- K2: B-find(global hist) + compact(regs->LDS) + hybrid bitonic + gather ----------------
__global__ __launch_bounds__(1024) void k_topsel(const unsigned* __restrict__ keys,
                                                 const int* __restrict__ clsArr,
                                                 const float* __restrict__ clean,
                                                 const float* __restrict__ patch,
                                                 const unsigned* __restrict__ hist,
                                                 float* __restrict__ boxesK,
                                                 int* __restrict__ clsK,
                                                 int* __restrict__ validK) {
#pragma clang fp contract(off)
  const int t = blockIdx.x;
  const unsigned K = (t < 8) ? 512u : 1024u;
  const float conf_th = (t < 8) ? 0.25f : 0.001f;
  __shared__ unsigned long long buf[CAP];   // 16 KB
  __shared__ unsigned scnt[2];
  __shared__ unsigned wtot[16], wsuf[16];
  __shared__ unsigned s_B;
  const int tid = threadIdx.x;
  const int lane = tid & 63, wv = tid >> 6;
  for (int i = tid; i < CAP; i += 1024) buf[i] = 0ull;
  if (tid < 2) scnt[tid] = 0u;
  const unsigned* kv = keys + (size_t)t * NA;
  // Preload ALL keys for phase C (7 x uint4 = 28 keys/thread); latency hides under phase B.
  const uint4* kv4 = (const uint4*)kv;
  uint4 u[7];
#pragma unroll
  for (int c = 0; c < 7; ++c) {
    const int i4 = c * 1024 + tid;
    if (i4 < NA / 4) u[c] = kv4[i4];
    else { u[c].x = 0u; u[c].y = 0u; u[c].z = 0u; u[c].w = 0u; }
  }
  // Phase B: per-thread 32-bin chunk from global hist (all static indices -> registers)
  unsigned hb[32];
  {
    const uint4* gh4 = (const uint4*)(hist + (size_t)t * NBIN + (size_t)tid * 32);
#pragma unroll
    for (int i = 0; i < 8; ++i) {
      uint4 h4 = gh4[i];
      hb[i * 4 + 0] = h4.x; hb[i * 4 + 1] = h4.y; hb[i * 4 + 2] = h4.z; hb[i * 4 + 3] = h4.w;
    }
  }
  unsigned cnt_c = 0;
#pragma unroll
  for (int i = 0; i < 32; ++i) cnt_c += hb[i];
  unsigned s = cnt_c;                       // wave-level inclusive suffix scan
  for (int off = 1; off < 64; off <<= 1) {
    unsigned v = __shfl_down(s, off);
    if (lane + off < 64) s += v;
  }
  if (lane == 0) wtot[wv] = s;
  __syncthreads();
  if (tid < 16) {
    unsigned acc = 0;
    for (int w2 = 15; w2 > tid; --w2) acc += wtot[w2];
    wsuf[tid] = acc;
  }
  __syncthreads();
  const unsigned suf = s + wsuf[wv];        // suffix over chunks [tid, 1023]
  if (suf >= K && suf - cnt_c < K) {
    // unique crossing thread owns the threshold chunk; walk bins high->low in registers
    unsigned acc = suf - cnt_c;             // count strictly above this chunk
    unsigned res = (unsigned)(tid * 32);
    bool found = false;
#pragma unroll
    for (int i = 31; i >= 0; --i) {
      const unsigned c2 = hb[i];
      if (!found) {
        if (acc + c2 >= K) { res = (unsigned)(tid * 32 + i); found = true; }
        else acc += c2;
      }
    }
    s_B = res;
  }
  __syncthreads();
  const unsigned B = s_B;
  // Phase C: compact from registers into LDS buf (ballot-aggregated LDS counters)
  const unsigned long long lowmask =
      (lane == 0) ? 0ull : (0xFFFFFFFFFFFFFFFFull >> (64 - lane));
#pragma unroll
  for (int c = 0; c < 7; ++c) {
    const int i4 = c * 1024 + tid;
    const bool inb = (i4 < NA / 4);
    unsigned kk[4] = {u[c].x, u[c].y, u[c].z, u[c].w};
#pragma unroll
    for (int e = 0; e < 4; ++e) {
      const unsigned key = kk[e];
      const unsigned p = key >> PSH;
      const bool hi = inb && (p > B);
      const bool eq = inb && (p == B);
      const int idx = i4 * 4 + e;
      const unsigned long long item =
          ((unsigned long long)key << 32) | (unsigned)(~(unsigned)idx);
      unsigned long long mh = __ballot(hi);
      if (mh) {
        int leader = (int)__ffsll(mh) - 1;
        unsigned base2 = 0;
        if (lane == leader) base2 = atomicAdd(&scnt[0], (unsigned)__popcll(mh));
        base2 = __shfl(base2, leader);
        if (hi) {
          unsigned pos = base2 + (unsigned)__popcll(mh & lowmask);
          if (pos < 1024u) buf[pos] = item;   // hi count < K <= 1024 guaranteed
        }
      }
      unsigned long long me = __ballot(eq);
      if (me) {
        int leader = (int)__ffsll(me) - 1;
        unsigned base2 = 0;
        if (lane == leader) base2 = atomicAdd(&scnt[1], (unsigned)__popcll(me));
        base2 = __shfl(base2, leader);
        if (eq) {
          unsigned pos = base2 + (unsigned)__popcll(me & lowmask);
          if (pos < 1024u) buf[1024 + pos] = item;  // clamp safe: overflow only all-masked entries
        }
      }
    }
  }
  __syncthreads();
  // Phase D: hybrid bitonic sort, descending; equal keys -> larger ~idx (= smaller idx) first.
  // 2048 elements live in registers: thread (wv,lane) owns e0 = wv*128+lane, e1 = e0+64.
  // j<=32 -> shfl_xor (no barrier); j==64 -> in-thread swap (no barrier); j>=128 -> LDS exchange.
  {
    const int e0 = wv * 128 + lane;
    const int e1 = e0 + 64;
    unsigned long long r0 = buf[e0], r1 = buf[e1];
    for (int kk2 = 2; kk2 <= CAP; kk2 <<= 1) {
      for (int j = kk2 >> 1; j > 0; j >>= 1) {
        if (j >= 128) {
          buf[e0] = r0; buf[e1] = r1;
          __syncthreads();
          unsigned long long o0 = buf[e0 ^ j];
          unsigned long long o1 = buf[e1 ^ j];
          // j >= 128 and kk2 >= 256: bits 6+ identical across (e0,e1) pair halves
          const bool mx = (((e0 & kk2) == 0) == ((e0 & j) == 0));
          r0 = mx ? (r0 > o0 ? r0 : o0) : (r0 < o0 ? r0 : o0);
          r1 = mx ? (r1 > o1 ? r1 : o1) : (r1 < o1 ? r1 : o1);
          __syncthreads();
        } else if (j == 64) {
          const bool up = (e0 & kk2) == 0;   // kk2 >= 128 here, same for e1
          unsigned long long mxv = r0 > r1 ? r0 : r1;
          unsigned long long mnv = r0 > r1 ? r1 : r0;
          r0 = up ? mxv : mnv;
          r1 = up ? mnv : mxv;
        } else {
          unsigned long long o0 = shflx64(r0, j);
          unsigned long long o1 = shflx64(r1, j);
          const bool up0 = (e0 & kk2) == 0;
          const bool up1 = (e1 & kk2) == 0;  // differs from up0 only when kk2 == 64
          const bool lo  = (lane & j) == 0;  // e&j == lane&j for j < 64
          const bool m0 = (up0 == lo), m1 = (up1 == lo);
          r0 = m0 ? (r0 > o0 ? r0 : o0) : (r0 < o0 ? r0 : o0);
          r1 = m1 ? (r1 > o1 ? r1 : o1) : (r1 < o1 ? r1 : o1);
        }
      }
    }
    buf[e0] = r0; buf[e1] = r1;
  }
  __syncthreads();
  // Phase E: gather top-K boxes/cls
  const float* __restrict__ src = ((t < 8) ? clean : patch) + (size_t)(t & 7) * NA * CH;
  const unsigned vkey = okey(conf_th);
  for (int k = tid; k < (int)K; k += 1024) {
    unsigned long long v = buf[k];
    unsigned key = (unsigned)(v >> 32);
    int idx = (int)(~(unsigned)(v & 0xFFFFFFFFull));
    if (idx < 0 || idx >= NA) idx = 0;  // padding entries (key 0) masked downstream
    const float* r = src + (size_t)idx * CH;
    float cx = r[0], cy = r[1], w = r[2], h = r[3];
    float hw = w * 0.5f, hh = h * 0.5f;
    float* bo = boxesK + ((size_t)t * KMAX + k) * 4;
    bo[0] = cx - hw; bo[1] = cy - hh; bo[2] = cx + hw; bo[3] = cy + hh;
    clsK[t * KMAX + k]   = clsArr[(size_t)t * NA + idx];
    validK[t * KMAX + k] = (key > vkey) ? 1 : 0;
  }
}

// ---------------- K3: suppression bit-matrix, triangular enumeration ----------------
__global__ __launch_bounds__(256) void k_ioumat(const float* __restrict__ boxesK,
                                                const int* __restrict__ clsK,
                                                unsigned long long* __restrict__ sup,
                                                unsigned long long* __restrict__ diag) {
#pragma clang fp contract(off)
  const int t  = blockIdx.y;
  const int K  = (t < 8) ? 512 : 1024;
  const int lw = (t < 8) ? 3 : 4;
  const int nw = 1 << lw;
  const int npair = (nw * (nw + 1)) / 2;
  const int total = npair * 64;
  if (blockIdx.x * 256 >= total) return;
  __shared__ float X1[KMAX + 16], Y1[KMAX + 16], X2[KMAX + 16], Y2[KMAX + 16], AR[KMAX + 16];
  for (int i = threadIdx.x; i < K; i += 256) {
    const float* bo = boxesK + ((size_t)t * KMAX + i) * 4;
    float off = (float)clsK[t * KMAX + i] * 4096.0f;
    float x1 = bo[0] + off, y1 = bo[1] + off, x2 = bo[2] + off, y2 = bo[3] + off;
    const int ip = i + (i >> 6);
    X1[ip] = x1; Y1[ip] = y1; X2[ip] = x2; Y2[ip] = y2;
    AR[ip] = (x2 - x1) * (y2 - y1);
  }
  __syncthreads();
  unsigned long long* supt = sup + (size_t)t * (KMAX * 16);
  for (int widx = blockIdx.x * 256 + threadIdx.x; widx < total; widx += IOB * 256) {
    int p = widx >> 6;
    int row = widx & 63;
    int rb = 0, pr = p;
    while (pr >= nw - rb) { pr -= nw - rb; ++rb; }
    const int wc = rb + pr;
    const int i = rb * 64 + row;
    const int ipi = i + rb;
    const float x1i = X1[ipi], y1i = Y1[ipi], x2i = X2[ipi], y2i = Y2[ipi], ai = AR[ipi];
    unsigned long long m = 0ull;
    const int jb = (wc << 6) + wc;
    const bool offd = (wc > rb);
#pragma unroll 4
    for (int l = 0; l < 64; ++l) {
      const int jp = jb + l;                    // wave-uniform -> LDS broadcast
      float tlx = fmaxf(x1i, X1[jp]);
      float tly = fmaxf(y1i, Y1[jp]);
      float brx = fminf(x2i, X2[jp]);
      float bry = fminf(y2i, Y2[jp]);
      float w = fmaxf(brx - tlx, 0.0f);
      float h = fmaxf(bry - tly, 0.0f);
      float inter = w * h;
      float uni = (ai + AR[jp]) - inter;
      uni = (uni > 0.0f) ? uni : 1.0f;
      float iou = inter / uni;                  // IEEE div, bit-matches ref compare
      bool hit = (iou > 0.45f) && (offd || ((wc << 6) + l > i));
      m |= hit ? (1ull << l) : 0ull;
    }
    supt[(size_t)i * nw + wc] = m;
    if (wc == rb) diag[(size_t)t * KMAX + i] = m;
  }
}

// ---------------- K4: greedy NMS — LDS diag chain + hoisted unconditional row gather ----------------
__global__ __launch_bounds__(64) void k_greedy(const unsigned long long* __restrict__ sup,
                                               const unsigned long long* __restrict__ diag,
                                               const int* __restrict__ validK,
                                               unsigned long long* __restrict__ keepw) {
  const int t  = blockIdx.x;
  const int K  = (t < 8) ? 512 : 1024;
  const int lw = (t < 8) ? 3 : 4;
  const int nw = 1 << lw;
  const int lane = threadIdx.x;
  __shared__ unsigned long long sdiag[KMAX];
  const unsigned long long* dg = diag + (size_t)t * KMAX;
  for (int i = lane; i < K; i += 64) sdiag[i] = dg[i];
  int v16[16];
#pragma unroll
  for (int W = 0; W < 16; ++W)
    v16[W] = (W < nw) ? validK[t * KMAX + W * 64 + lane] : 0;
  unsigned long long vkeep = 0ull;
#pragma unroll
  for (int W = 0; W < 16; ++W)
    if (W < nw) {
      unsigned long long bl = __ballot(v16[W] != 0);
      if (lane == W) vkeep = bl;
    }
  __syncthreads();
  const int w = lane & (nw - 1);
  const int b = lane >> lw;
  const int r0 = b * nw;
  const unsigned long long* base = sup + (size_t)t * (KMAX * 16);
  unsigned long long remv = 0ull;
  for (int W = 0; W < nw; ++W) {
    // Hoisted gather: addresses depend only on W (not on cur); latency hides under diag chain.
    unsigned long long vv[16];
    if (W + 1 < nw) {
#pragma unroll
      for (int j = 0; j < 16; ++j)
        vv[j] = (j < nw) ? base[(size_t)(W * 64 + r0 + j) * nw + w] : 0ull;
    }
    unsigned long long cur = __shfl(vkeep, W) & ~__shfl(remv, W);
    for (int rb = 0; rb < 64; rb += 16) {
      unsigned long long tm[16];
#pragma unroll
      for (int i2 = 0; i2 < 16; ++i2) tm[i2] = sdiag[W * 64 + rb + i2];
#pragma unroll
      for (int i2 = 0; i2 < 16; ++i2) {
        unsigned long long msk = 0ull - ((cur >> (rb + i2)) & 1ull);
        cur &= ~(tm[i2] & msk);
      }
    }
    if (lane == 0) keepw[t * 16 + W] = cur;
    if (W + 1 < nw) {
      unsigned long long part = 0ull;
#pragma unroll
      for (int j = 0; j < 16; ++j) {
        bool take = (j < nw) && (w > W) && ((cur >> (r0 + j)) & 1ull);
        part |= take ? vv[j] : 0ull;
      }
      for (int s = nw; s < 64; s <<= 1) part |= __shfl_xor(part, s);
      remv |= part;
    }
  }
}

// ---------------- K5: masked-max IoU loss partials (1024 thr, 16 stripes) ----------------
__global__ __launch_bounds__(1024) void k_loss(const float* __restrict__ boxesK,
                                               const int* __restrict__ clsK,
                                               const unsigned long long* __restrict__ keepw,
                                               float* __restrict__ part) {
#pragma clang fp contract(off)
  const int img = blockIdx.y;
  const int chunk = blockIdx.x;
  const int tp = 8 + img;
  __shared__ float px1[KMAX], py1[KMAX], px2[KMAX], py2[KMAX], pa[KMAX];
  __shared__ int pcls[KMAX];
  __shared__ float red[1024];
  for (int j = threadIdx.x; j < KMAX; j += 1024) {
    const float* bo = boxesK + ((size_t)tp * KMAX + j) * 4;
    float x1 = bo[0] / 640.0f, y1 = bo[1] / 640.0f;
    float x2 = bo[2] / 640.0f, y2 = bo[3] / 640.0f;
    px1[j] = x1; py1[j] = y1; px2[j] = x2; py2[j] = y2;
    pa[j] = (x2 - x1) * (y2 - y1);
    int kept = (int)((keepw[tp * 16 + (j >> 6)] >> (j & 63)) & 1ull);
    pcls[j] = kept ? clsK[tp * KMAX + j] : -1;
  }
  __syncthreads();
  const int row = chunk * 64 + (threadIdx.x & 63);
  const int stripe = threadIdx.x >> 6;
  const int ck = (int)((keepw[img * 16 + (row >> 6)] >> (row & 63)) & 1ull);
  const float* bo = boxesK + ((size_t)img * KMAX + row) * 4;
  float cx1 = bo[0] / 640.0f, cy1 = bo[1] / 640.0f;
  float cx2 = bo[2] / 640.0f, cy2 = bo[3] / 640.0f;
  float ca = (cx2 - cx1) * (cy2 - cy1);
  const int ccls = clsK[img * KMAX + row];
  float m = 0.0f;
  if (ck) {
    const int j0 = stripe * 64;
    for (int j = j0; j < j0 + 64; ++j) {
      if (pcls[j] == ccls) {
        float tlx = fmaxf(cx1, px1[j]);
        float tly = fmaxf(cy1, py1[j]);
        float brx = fminf(cx2, px2[j]);
        float bry = fminf(cy2, py2[j]);
        float w = fmaxf(brx - tlx, 0.0f);
        float h = fmaxf(bry - tly, 0.0f);
        float inter = w * h;
        float uni = (ca + pa[j]) - inter;
        uni = (uni > 0.0f) ? uni : 1.0f;
        m = fmaxf(m, inter / uni);
      }
    }
  }
  red[threadIdx.x] = m;
  __syncthreads();
  if (threadIdx.x < 64) {
    float mm = red[threadIdx.x];
#pragma unroll
    for (int s = 1; s < 16; ++s) mm = fmaxf(mm, red[threadIdx.x + 64 * s]);
    float sv = ck ? mm : 0.0f;
    float nv = ck ? 1.0f : 0.0f;
    for (int off = 32; off > 0; off >>= 1) {
      sv += __shfl_down(sv, off);
      nv += __shfl_down(nv, off);
    }
    if (threadIdx.x == 0) {
      int b = img * 8 + chunk;
      part[b * 2 + 0] = sv;
      part[b * 2 + 1] = nv;
    }
  }
}

// ---------------- K6: deterministic final reduce ----------------
__global__ __launch_bounds__(64) void k_final(const float* __restrict__ part,
                                              float* __restrict__ out) {
  int lane = threadIdx.x;
  float sv = part[lane * 2 + 0];
  float nv = part[lane * 2 + 1];
  for (int off = 32; off > 0; off >>= 1) {
    sv += __shfl_down(sv, off);
    nv += __shfl_down(nv, off);
  }
  if (lane == 0) out[0] = (nv > 0.0f) ? (1.0f - sv / fmaxf(nv, 1.0f)) : 1.0f;
}

extern "C" void kernel_launch(void* const* d_in, const int* in_sizes, int n_in,
                              void* d_out, int out_size, void* d_ws, size_t ws_size,
                              hipStream_t stream) {
  const float* clean = (const float*)d_in[0];
  const float* patch = (const float*)d_in[1];
  char* ws = (char*)d_ws;
  unsigned* keys            = (unsigned*)(ws + OFF_KEYS);
  int* clsArr               = (int*)(ws + OFF_CLS);
  float* boxesK             = (float*)(ws + OFF_BOX);
  int* clsK                 = (int*)(ws + OFF_CLSK);
  int* validK               = (int*)(ws + OFF_VALK);
  unsigned long long* keepw = (unsigned long long*)(ws + OFF_KEEP);
  unsigned long long* sup   = (unsigned long long*)(ws + OFF_SUP);
  unsigned long long* diag  = (unsigned long long*)(ws + OFF_DIAG);
  float* part               = (float*)(ws + OFF_PART);
  unsigned* hist            = (unsigned*)(ws + OFF_HIST);
  float* out                = (float*)d_out;

  k_zero   <<<(NT * NBIN * 4) / (16 * 256), 256, 0, stream>>>((uint4*)hist);
  k_score  <<<dim3((NA + 63) / 64, NT), 256, 0, stream>>>(clean, patch, keys, clsArr, hist);
  k_topsel <<<NT, 1024, 0, stream>>>(keys, clsArr, clean, patch, hist, boxesK, clsK, validK);
  k_ioumat <<<dim3(IOB, NT), 256, 0, stream>>>(boxesK, clsK, sup, diag);
  k_greedy <<<NT, 64, 0, stream>>>(sup, diag, validK, keepw);
  k_loss   <<<dim3(8, NB), 1024, 0, stream>>>(boxesK, clsK, keepw, part);
  k_final  <<<1, 64, 0, stream>>>(part, out);
}

// Round 6
// 245.013 us; speedup vs baseline: 1.2916x; 1.2916x over previous
//
#include <hip/hip_runtime.h>

// Pipeline (6 launches): k_score (async LDS staging) -> k_topsel (hist+select+compact+sort+gather)
//                        -> k_ioumat(+diag, triangular) -> k_greedy -> k_loss -> k_final
// R1: k_topsel phase D hybrid register/shuffle bitonic (10 LDS stages + 56 barrier-free).
// R4: k_score NT staging; k_greedy hoisted unconditional row gather.  [best: 247.9 us]
// R5: FAILED — global fused histogram serialized on ~hundreds of hot bins (k_score 2x).
// R6: revert R5's global hist; keep its one independent win: k_topsel preloads ALL keys
//     into registers once (issued before LDS init, latency hidden), feeding BOTH the LDS
//     histogram (phase A) and the compaction (phase C) — kills the exposed-latency re-read.

static constexpr int NB   = 8;
static constexpr int NA   = 25200;
static constexpr int NCLS = 80;
static constexpr int CH   = 85;
static constexpr int NT   = 16;    // 8 clean + 8 patch tasks
static constexpr int KMAX = 1024;
static constexpr int NBIN = 32768; // 15-bit prefix bins
static constexpr int PSH  = 17;    // key >> PSH = bin
static constexpr int CAP  = 2048;  // candidate buffer (hi[0,1024) eq[1024,2048))
static constexpr int IOB  = 34;    // x-blocks for k_ioumat (patch: 136 pairs*64 rows = 34*256)

// workspace byte offsets (all 16B aligned)
static constexpr size_t OFF_KEYS = 0;                                     // 1,612,800
static constexpr size_t OFF_CLS  = OFF_KEYS + (size_t)NT * NA * 4;        // 1,612,800
static constexpr size_t OFF_BOX  = OFF_CLS  + (size_t)NT * NA * 4;        // 262,144
static constexpr size_t OFF_CLSK = OFF_BOX  + (size_t)NT * KMAX * 16;     // 65,536
static constexpr size_t OFF_VALK = OFF_CLSK + (size_t)NT * KMAX * 4;      // 65,536
static constexpr size_t OFF_KEEP = OFF_VALK + (size_t)NT * KMAX * 4;      // 2,048
static constexpr size_t OFF_SUP  = OFF_KEEP + (size_t)NT * 16 * 8;        // 2,097,152
static constexpr size_t OFF_DIAG = OFF_SUP  + (size_t)NT * KMAX * 16 * 8; // 131,072
static constexpr size_t OFF_PART = OFF_DIAG + (size_t)NT * KMAX * 8;      // 512
// total ~5.85 MB

__device__ __forceinline__ unsigned okey(float f) {
  unsigned u = __float_as_uint(f);
  return (u & 0x80000000u) ? ~u : (u | 0x80000000u);
}

__device__ __forceinline__ unsigned long long shflx64(unsigned long long v, int m) {
  unsigned lo = (unsigned)v, hi = (unsigned)(v >> 32);
  lo = __shfl_xor(lo, m);
  hi = __shfl_xor(hi, m);
  return ((unsigned long long)hi << 32) | lo;
}

// ---------------- K1: per-anchor score/class — per-wave async NT staging, no barrier ----------------
__global__ __launch_bounds__(256) void k_score(const float* __restrict__ clean,
                                               const float* __restrict__ patch,
                                               unsigned* __restrict__ keys,
                                               int* __restrict__ clsArr) {
#pragma clang fp contract(off)
  __shared__ float rows[4][16 * CH];  // per-wave slices, 4 x 5440 B (no cross-wave sharing)
  const int t    = blockIdx.y;
  const int wave = threadIdx.x >> 6;
  const int lane = threadIdx.x & 63;
  const int a0   = blockIdx.x * 64 + wave * 16;  // this wave's 16 anchors (NA % 16 == 0)
  if (a0 >= NA) return;                          // empty wave in last block only
  const float conf_th = (t < 8) ? 0.25f : 0.001f;
  const float* __restrict__ src = ((t < 8) ? clean : patch) + (size_t)(t & 7) * NA * CH;
  const float4* g4 = (const float4*)(src + (size_t)a0 * CH);  // a0*85 % 4 == 0 -> 16B aligned
  float4* rows4 = (float4*)rows[wave];
  // stage 16*85 = 1360 floats = 340 float4; aux=2 -> NT (no L2/L3 allocate)
#pragma unroll
  for (int c = 0; c < 6; ++c) {
    const int i = (c << 6) + lane;  // lds dst = uniform base + lane*16
    if (i < 340) {
      __builtin_amdgcn_global_load_lds(
          (const __attribute__((address_space(1))) void*)(g4 + i),
          (__attribute__((address_space(3))) void*)(rows4 + (c << 6)),
          16, 0, 2 /* NT */);
    }
  }
  // vmcnt is per-wave: wait only on our own staging loads, no __syncthreads.
  asm volatile("s_waitcnt vmcnt(0)" ::: "memory");
  __builtin_amdgcn_sched_barrier(0);

  const int ar = lane >> 2;  // 0..15
  const int q  = lane & 3;
  const float* r = rows[wave] + ar * CH;
  const float obj = r[4];
  const int c0 = q * 20;
  float best = r[5 + c0] * obj;  // products first (matches ref argmax over cls_conf)
  int bc = c0;
  for (int c = c0 + 1; c < c0 + 20; ++c) {
    float v = r[5 + c] * obj;
    if (v > best) { best = v; bc = c; }
  }
  {
    float b2 = __shfl_down(best, 2); int c2 = __shfl_down(bc, 2);
    if (b2 > best || (b2 == best && c2 < bc)) { best = b2; bc = c2; }
    float b1 = __shfl_down(best, 1); int c1 = __shfl_down(bc, 1);
    if (b1 > best || (b1 == best && c1 < bc)) { best = b1; bc = c1; }
  }
  if (q == 0) {
    const bool valid = (obj > conf_th) && (best > conf_th);
    const float score = valid ? best : -1e30f;
    const int a = a0 + ar;
    keys[(size_t)t * NA + a]   = okey(score);
    clsArr[(size_t)t * NA + a] = bc;
  }
}

// ---------------- K2: fused hist + select + compact + hybrid bitonic + gather (keys in regs) ----------------
__global__ __launch_bounds__(1024) void k_topsel(const unsigned* __restrict__ keys,
                                                 const int* __restrict__ clsArr,
                                                 const float* __restrict__ clean,
                                                 const float* __restrict__ patch,
                                                 float* __restrict__ boxesK,
                                                 int* __restrict__ clsK,
                                                 int* __restrict__ validK) {
#pragma clang fp contract(off)
  const int t = blockIdx.x;
  const unsigned K = (t < 8) ? 512u : 1024u;
  const float conf_th = (t < 8) ? 0.25f : 0.001f;
  __shared__ unsigned h32[NBIN / 2];        // 64 KB: two 16-bit bins per word
  __shared__ unsigned long long buf[CAP];   // 16 KB
  __shared__ unsigned scnt[2];
  __shared__ unsigned wtot[16], wsuf[16];
  __shared__ int s_chunk;
  __shared__ unsigned s_acc, s_B;
  const int tid = threadIdx.x;
  const int lane = tid & 63, wv = tid >> 6;
  // Preload ALL keys into registers FIRST (7 x uint4 = 28 keys/thread); the loads'
  // HBM/L2 latency hides under the LDS zero-init + barrier below.
  const unsigned* kv = keys + (size_t)t * NA;
  const uint4* kv4 = (const uint4*)kv;
  uint4 u[7];
#pragma unroll
  for (int c = 0; c < 7; ++c) {
    const int i4 = c * 1024 + tid;
    if (i4 < NA / 4) u[c] = kv4[i4];
    else { u[c].x = 0u; u[c].y = 0u; u[c].z = 0u; u[c].w = 0u; }
  }
  for (int i = tid; i < NBIN / 2; i += 1024) h32[i] = 0u;
  for (int i = tid; i < CAP; i += 1024) buf[i] = 0ull;
  if (tid < 2) scnt[tid] = 0u;
  __syncthreads();
  const unsigned INVKEY = okey(-1e30f);
  // Phase A: histogram from registers; invalid keys counted per-lane, one atomic at end
  {
    unsigned invCnt = 0;
#pragma unroll
    for (int c = 0; c < 7; ++c) {
      const int i4 = c * 1024 + tid;
      if (i4 < NA / 4) {
        unsigned kk[4] = {u[c].x, u[c].y, u[c].z, u[c].w};
#pragma unroll
        for (int e = 0; e < 4; ++e) {
          if (kk[e] == INVKEY) {
            ++invCnt;
          } else {
            unsigned b = kk[e] >> PSH;
            atomicAdd(&h32[b >> 1], 1u << ((b & 1) * 16));
          }
        }
      }
    }
    for (int off = 32; off > 0; off >>= 1) invCnt += __shfl_down(invCnt, off);
    if (lane == 0 && invCnt) {
      unsigned b = INVKEY >> PSH;
      atomicAdd(&h32[b >> 1], invCnt << ((b & 1) * 16));
    }
  }
  __syncthreads();
  // Phase B: chunk sums (32 bins/chunk) + hierarchical suffix scan (3 barriers)
  unsigned cnt_c = 0;
  for (int i = 0; i < 16; ++i) {
    unsigned v = h32[tid * 16 + i];
    cnt_c += (v & 0xFFFFu) + (v >> 16);
  }
  unsigned s = cnt_c;                       // wave-level inclusive suffix scan
  for (int off = 1; off < 64; off <<= 1) {
    unsigned v = __shfl_down(s, off);
    if (lane + off < 64) s += v;
  }
  if (lane == 0) wtot[wv] = s;
  __syncthreads();
  if (tid < 16) {
    unsigned acc = 0;
    for (int w2 = 15; w2 > tid; --w2) acc += wtot[w2];
    wsuf[tid] = acc;
  }
  __syncthreads();
  const unsigned suf = s + wsuf[wv];        // suffix over chunks [tid, 1023]
  if (suf >= K && suf - cnt_c < K) { s_chunk = tid; s_acc = suf - cnt_c; }
  __syncthreads();
  if (tid == 0) {
    unsigned acc = s_acc;
    unsigned res = (unsigned)(s_chunk * 32);
    for (int i = 31; i >= 0; --i) {
      int bb = s_chunk * 32 + i;
      unsigned v = h32[bb >> 1];
      unsigned c2 = (bb & 1) ? (v >> 16) : (v & 0xFFFFu);
      if (acc + c2 >= K) { res = (unsigned)bb; break; }
      acc += c2;
    }
    s_B = res;
  }
  __syncthreads();
  const unsigned B = s_B;
  // Phase C: compact from registers into LDS buf (ballot-aggregated LDS counters)
  const unsigned long long lowmask =
      (lane == 0) ? 0ull : (0xFFFFFFFFFFFFFFFFull >> (64 - lane));
#pragma unroll
  for (int c = 0; c < 7; ++c) {
    const int i4 = c * 1024 + tid;
    const bool inb = (i4 < NA / 4);
    unsigned kk[4] = {u[c].x, u[c].y, u[c].z, u[c].w};
#pragma unroll
    for (int e = 0; e < 4; ++e) {
      const unsigned key = kk[e];
      const unsigned p = key >> PSH;
      const bool hi = inb && (p > B);
      const bool eq = inb && (p == B);
      const int idx = i4 * 4 + e;
      const unsigned long long item =
          ((unsigned long long)key << 32) | (unsigned)(~(unsigned)idx);
      unsigned long long mh = __ballot(hi);
      if (mh) {
        int leader = (int)__ffsll(mh) - 1;
        unsigned base2 = 0;
        if (lane == leader) base2 = atomicAdd(&scnt[0], (unsigned)__popcll(mh));
        base2 = __shfl(base2, leader);
        if (hi) {
          unsigned pos = base2 + (unsigned)__popcll(mh & lowmask);
          if (pos < 1024u) buf[pos] = item;   // hi count < K <= 1024 guaranteed
        }
      }
      unsigned long long me = __ballot(eq);
      if (me) {
        int leader = (int)__ffsll(me) - 1;
        unsigned base2 = 0;
        if (lane == leader) base2 = atomicAdd(&scnt[1], (unsigned)__popcll(me));
        base2 = __shfl(base2, leader);
        if (eq) {
          unsigned pos = base2 + (unsigned)__popcll(me & lowmask);
          if (pos < 1024u) buf[1024 + pos] = item;  // clamp safe: overflow only all-masked entries
        }
      }
    }
  }
  __syncthreads();
  // Phase D: hybrid bitonic sort, descending; equal keys -> larger ~idx (= smaller idx) first.
  // 2048 elements live in registers: thread (wv,lane) owns e0 = wv*128+lane, e1 = e0+64.
  // j<=32 -> shfl_xor (no barrier); j==64 -> in-thread swap (no barrier); j>=128 -> LDS exchange.
  {
    const int e0 = wv * 128 + lane;
    const int e1 = e0 + 64;
    unsigned long long r0 = buf[e0], r1 = buf[e1];
    for (int kk2 = 2; kk2 <= CAP; kk2 <<= 1) {
      for (int j = kk2 >> 1; j > 0; j >>= 1) {
        if (j >= 128) {
          buf[e0] = r0; buf[e1] = r1;
          __syncthreads();
          unsigned long long o0 = buf[e0 ^ j];
          unsigned long long o1 = buf[e1 ^ j];
          // j >= 128 and kk2 >= 256: bits 6+ identical across (e0,e1) pair halves
          const bool mx = (((e0 & kk2) == 0) == ((e0 & j) == 0));
          r0 = mx ? (r0 > o0 ? r0 : o0) : (r0 < o0 ? r0 : o0);
          r1 = mx ? (r1 > o1 ? r1 : o1) : (r1 < o1 ? r1 : o1);
          __syncthreads();
        } else if (j == 64) {
          const bool up = (e0 & kk2) == 0;   // kk2 >= 128 here, same for e1
          unsigned long long mxv = r0 > r1 ? r0 : r1;
          unsigned long long mnv = r0 > r1 ? r1 : r0;
          r0 = up ? mxv : mnv;
          r1 = up ? mnv : mxv;
        } else {
          unsigned long long o0 = shflx64(r0, j);
          unsigned long long o1 = shflx64(r1, j);
          const bool up0 = (e0 & kk2) == 0;
          const bool up1 = (e1 & kk2) == 0;  // differs from up0 only when kk2 == 64
          const bool lo  = (lane & j) == 0;  // e&j == lane&j for j < 64
          const bool m0 = (up0 == lo), m1 = (up1 == lo);
          r0 = m0 ? (r0 > o0 ? r0 : o0) : (r0 < o0 ? r0 : o0);
          r1 = m1 ? (r1 > o1 ? r1 : o1) : (r1 < o1 ? r1 : o1);
        }
      }
    }
    buf[e0] = r0; buf[e1] = r1;
  }
  __syncthreads();
  // Phase E: gather top-K boxes/cls
  const float* __restrict__ src = ((t < 8) ? clean : patch) + (size_t)(t & 7) * NA * CH;
  const unsigned vkey = okey(conf_th);
  for (int k = tid; k < (int)K; k += 1024) {
    unsigned long long v = buf[k];
    unsigned key = (unsigned)(v >> 32);
    int idx = (int)(~(unsigned)(v & 0xFFFFFFFFull));
    if (idx < 0 || idx >= NA) idx = 0;  // padding entries (key 0) masked downstream
    const float* r = src + (size_t)idx * CH;
    float cx = r[0], cy = r[1], w = r[2], h = r[3];
    float hw = w * 0.5f, hh = h * 0.5f;
    float* bo = boxesK + ((size_t)t * KMAX + k) * 4;
    bo[0] = cx - hw; bo[1] = cy - hh; bo[2] = cx + hw; bo[3] = cy + hh;
    clsK[t * KMAX + k]   = clsArr[(size_t)t * NA + idx];
    validK[t * KMAX + k] = (key > vkey) ? 1 : 0;
  }
}

// ---------------- K3: suppression bit-matrix, triangular enumeration ----------------
__global__ __launch_bounds__(256) void k_ioumat(const float* __restrict__ boxesK,
                                                const int* __restrict__ clsK,
                                                unsigned long long* __restrict__ sup,
                                                unsigned long long* __restrict__ diag) {
#pragma clang fp contract(off)
  const int t  = blockIdx.y;
  const int K  = (t < 8) ? 512 : 1024;
  const int lw = (t < 8) ? 3 : 4;
  const int nw = 1 << lw;
  const int npair = (nw * (nw + 1)) / 2;
  const int total = npair * 64;
  if (blockIdx.x * 256 >= total) return;
  __shared__ float X1[KMAX + 16], Y1[KMAX + 16], X2[KMAX + 16], Y2[KMAX + 16], AR[KMAX + 16];
  for (int i = threadIdx.x; i < K; i += 256) {
    const float* bo = boxesK + ((size_t)t * KMAX + i) * 4;
    float off = (float)clsK[t * KMAX + i] * 4096.0f;
    float x1 = bo[0] + off, y1 = bo[1] + off, x2 = bo[2] + off, y2 = bo[3] + off;
    const int ip = i + (i >> 6);
    X1[ip] = x1; Y1[ip] = y1; X2[ip] = x2; Y2[ip] = y2;
    AR[ip] = (x2 - x1) * (y2 - y1);
  }
  __syncthreads();
  unsigned long long* supt = sup + (size_t)t * (KMAX * 16);
  for (int widx = blockIdx.x * 256 + threadIdx.x; widx < total; widx += IOB * 256) {
    int p = widx >> 6;
    int row = widx & 63;
    int rb = 0, pr = p;
    while (pr >= nw - rb) { pr -= nw - rb; ++rb; }
    const int wc = rb + pr;
    const int i = rb * 64 + row;
    const int ipi = i + rb;
    const float x1i = X1[ipi], y1i = Y1[ipi], x2i = X2[ipi], y2i = Y2[ipi], ai = AR[ipi];
    unsigned long long m = 0ull;
    const int jb = (wc << 6) + wc;
    const bool offd = (wc > rb);
#pragma unroll 4
    for (int l = 0; l < 64; ++l) {
      const int jp = jb + l;                    // wave-uniform -> LDS broadcast
      float tlx = fmaxf(x1i, X1[jp]);
      float tly = fmaxf(y1i, Y1[jp]);
      float brx = fminf(x2i, X2[jp]);
      float bry = fminf(y2i, Y2[jp]);
      float w = fmaxf(brx - tlx, 0.0f);
      float h = fmaxf(bry - tly, 0.0f);
      float inter = w * h;
      float uni = (ai + AR[jp]) - inter;
      uni = (uni > 0.0f) ? uni : 1.0f;
      float iou = inter / uni;                  // IEEE div, bit-matches ref compare
      bool hit = (iou > 0.45f) && (offd || ((wc << 6) + l > i));
      m |= hit ? (1ull << l) : 0ull;
    }
    supt[(size_t)i * nw + wc] = m;
    if (wc == rb) diag[(size_t)t * KMAX + i] = m;
  }
}

// ---------------- K4: greedy NMS — LDS diag chain + hoisted unconditional row gather ----------------
__global__ __launch_bounds__(64) void k_greedy(const unsigned long long* __restrict__ sup,
                                               const unsigned long long* __restrict__ diag,
                                               const int* __restrict__ validK,
                                               unsigned long long* __restrict__ keepw) {
  const int t  = blockIdx.x;
  const int K  = (t < 8) ? 512 : 1024;
  const int lw = (t < 8) ? 3 : 4;
  const int nw = 1 << lw;
  const int lane = threadIdx.x;
  __shared__ unsigned long long sdiag[KMAX];
  const unsigned long long* dg = diag + (size_t)t * KMAX;
  for (int i = lane; i < K; i += 64) sdiag[i] = dg[i];
  int v16[16];
#pragma unroll
  for (int W = 0; W < 16; ++W)
    v16[W] = (W < nw) ? validK[t * KMAX + W * 64 + lane] : 0;
  unsigned long long vkeep = 0ull;
#pragma unroll
  for (int W = 0; W < 16; ++W)
    if (W < nw) {
      unsigned long long bl = __ballot(v16[W] != 0);
      if (lane == W) vkeep = bl;
    }
  __syncthreads();
  const int w = lane & (nw - 1);
  const int b = lane >> lw;
  const int r0 = b * nw;
  const unsigned long long* base = sup + (size_t)t * (KMAX * 16);
  unsigned long long remv = 0ull;
  for (int W = 0; W < nw; ++W) {
    // Hoisted gather: addresses depend only on W (not on cur); latency hides under diag chain.
    unsigned long long vv[16];
    if (W + 1 < nw) {
#pragma unroll
      for (int j = 0; j < 16; ++j)
        vv[j] = (j < nw) ? base[(size_t)(W * 64 + r0 + j) * nw + w] : 0ull;
    }
    unsigned long long cur = __shfl(vkeep, W) & ~__shfl(remv, W);
    for (int rb = 0; rb < 64; rb += 16) {
      unsigned long long tm[16];
#pragma unroll
      for (int i2 = 0; i2 < 16; ++i2) tm[i2] = sdiag[W * 64 + rb + i2];
#pragma unroll
      for (int i2 = 0; i2 < 16; ++i2) {
        unsigned long long msk = 0ull - ((cur >> (rb + i2)) & 1ull);
        cur &= ~(tm[i2] & msk);
      }
    }
    if (lane == 0) keepw[t * 16 + W] = cur;
    if (W + 1 < nw) {
      unsigned long long part = 0ull;
#pragma unroll
      for (int j = 0; j < 16; ++j) {
        bool take = (j < nw) && (w > W) && ((cur >> (r0 + j)) & 1ull);
        part |= take ? vv[j] : 0ull;
      }
      for (int s = nw; s < 64; s <<= 1) part |= __shfl_xor(part, s);
      remv |= part;
    }
  }
}

// ---------------- K5: masked-max IoU loss partials (1024 thr, 16 stripes) ----------------
__global__ __launch_bounds__(1024) void k_loss(const float* __restrict__ boxesK,
                                               const int* __restrict__ clsK,
                                               const unsigned long long* __restrict__ keepw,
                                               float* __restrict__ part) {
#pragma clang fp contract(off)
  const int img = blockIdx.y;
  const int chunk = blockIdx.x;
  const int tp = 8 + img;
  __shared__ float px1[KMAX], py1[KMAX], px2[KMAX], py2[KMAX], pa[KMAX];
  __shared__ int pcls[KMAX];
  __shared__ float red[1024];
  for (int j = threadIdx.x; j < KMAX; j += 1024) {
    const float* bo = boxesK + ((size_t)tp * KMAX + j) * 4;
    float x1 = bo[0] / 640.0f, y1 = bo[1] / 640.0f;
    float x2 = bo[2] / 640.0f, y2 = bo[3] / 640.0f;
    px1[j] = x1; py1[j] = y1; px2[j] = x2; py2[j] = y2;
    pa[j] = (x2 - x1) * (y2 - y1);
    int kept = (int)((keepw[tp * 16 + (j >> 6)] >> (j & 63)) & 1ull);
    pcls[j] = kept ? clsK[tp * KMAX + j] : -1;
  }
  __syncthreads();
  const int row = chunk * 64 + (threadIdx.x & 63);
  const int stripe = threadIdx.x >> 6;
  const int ck = (int)((keepw[img * 16 + (row >> 6)] >> (row & 63)) & 1ull);
  const float* bo = boxesK + ((size_t)img * KMAX + row) * 4;
  float cx1 = bo[0] / 640.0f, cy1 = bo[1] / 640.0f;
  float cx2 = bo[2] / 640.0f, cy2 = bo[3] / 640.0f;
  float ca = (cx2 - cx1) * (cy2 - cy1);
  const int ccls = clsK[img * KMAX + row];
  float m = 0.0f;
  if (ck) {
    const int j0 = stripe * 64;
    for (int j = j0; j < j0 + 64; ++j) {
      if (pcls[j] == ccls) {
        float tlx = fmaxf(cx1, px1[j]);
        float tly = fmaxf(cy1, py1[j]);
        float brx = fminf(cx2, px2[j]);
        float bry = fminf(cy2, py2[j]);
        float w = fmaxf(brx - tlx, 0.0f);
        float h = fmaxf(bry - tly, 0.0f);
        float inter = w * h;
        float uni = (ca + pa[j]) - inter;
        uni = (uni > 0.0f) ? uni : 1.0f;
        m = fmaxf(m, inter / uni);
      }
    }
  }
  red[threadIdx.x] = m;
  __syncthreads();
  if (threadIdx.x < 64) {
    float mm = red[threadIdx.x];
#pragma unroll
    for (int s = 1; s < 16; ++s) mm = fmaxf(mm, red[threadIdx.x + 64 * s]);
    float sv = ck ? mm : 0.0f;
    float nv = ck ? 1.0f : 0.0f;
    for (int off = 32; off > 0; off >>= 1) {
      sv += __shfl_down(sv, off);
      nv += __shfl_down(nv, off);
    }
    if (threadIdx.x == 0) {
      int b = img * 8 + chunk;
      part[b * 2 + 0] = sv;
      part[b * 2 + 1] = nv;
    }
  }
}

// ---------------- K6: deterministic final reduce ----------------
__global__ __launch_bounds__(64) void k_final(const float* __restrict__ part,
                                              float* __restrict__ out) {
  int lane = threadIdx.x;
  float sv = part[lane * 2 + 0];
  float nv = part[lane * 2 + 1];
  for (int off = 32; off > 0; off >>= 1) {
    sv += __shfl_down(sv, off);
    nv += __shfl_down(nv, off);
  }
  if (lane == 0) out[0] = (nv > 0.0f) ? (1.0f - sv / fmaxf(nv, 1.0f)) : 1.0f;
}

extern "C" void kernel_launch(void* const* d_in, const int* in_sizes, int n_in,
                              void* d_out, int out_size, void* d_ws, size_t ws_size,
                              hipStream_t stream) {
  const float* clean = (const float*)d_in[0];
  const float* patch = (const float*)d_in[1];
  char* ws = (char*)d_ws;
  unsigned* keys            = (unsigned*)(ws + OFF_KEYS);
  int* clsArr               = (int*)(ws + OFF_CLS);
  float* boxesK             = (float*)(ws + OFF_BOX);
  int* clsK                 = (int*)(ws + OFF_CLSK);
  int* validK               = (int*)(ws + OFF_VALK);
  unsigned long long* keepw = (unsigned long long*)(ws + OFF_KEEP);
  unsigned long long* sup   = (unsigned long long*)(ws + OFF_SUP);
  unsigned long long* diag  = (unsigned long long*)(ws + OFF_DIAG);
  float* part               = (float*)(ws + OFF_PART);
  float* out                = (float*)d_out;

  k_score  <<<dim3((NA + 63) / 64, NT), 256, 0, stream>>>(clean, patch, keys, clsArr);
  k_topsel <<<NT, 1024, 0, stream>>>(keys, clsArr, clean, patch, boxesK, clsK, validK);
  k_ioumat <<<dim3(IOB, NT), 256, 0, stream>>>(boxesK, clsK, sup, diag);
  k_greedy <<<NT, 64, 0, stream>>>(sup, diag, validK, keepw);
  k_loss   <<<dim3(8, NB), 1024, 0, stream>>>(boxesK, clsK, keepw, part);
  k_final  <<<1, 64, 0, stream>>>(part, out);
}